// Round 5
// baseline (805.380 us; speedup 1.0000x reference)
//
#include <hip/hip_runtime.h>
#include <stdint.h>
#include <math.h>

#define B_  4
#define S_  2048
#define H_  2048
#define NH_ 16
#define HD_ 128
#define M_  (B_*S_)     // 8192 rows
#define N3_ (3*H_)      // 6144
#define NQT_ (S_/64)    // 32 q-tiles of 64 rows
#define NT_ (H_/64)     // 32 K-tiles for the GEMMs

typedef __attribute__((ext_vector_type(8))) short short8;
typedef __attribute__((ext_vector_type(4))) float floatx4;
typedef unsigned int u32;

__device__ __forceinline__ unsigned short f2bf(float f) {
  unsigned u = __float_as_uint(f);
  u += 0x7FFF + ((u >> 16) & 1);          // round-to-nearest-even
  return (unsigned short)(u >> 16);
}

// async 16B global -> LDS (global_load_lds_dwordx4). LDS dest must be
// wave-uniform base + lane*16 (no per-lane scatter / padding!).
__device__ __forceinline__ void gl2lds16(const void* g, void* l) {
  __builtin_amdgcn_global_load_lds(
      (const __attribute__((address_space(1))) u32*)g,
      (__attribute__((address_space(3))) u32*)l, 16, 0, 0);
}

// ---------------------------------------------------------------- LayerNorm
__global__ __launch_bounds__(256) void ln_kernel(
    const float* __restrict__ x, const float* __restrict__ w,
    const float* __restrict__ b, unsigned short* __restrict__ xn) {
  int row = blockIdx.x;
  int t = threadIdx.x;
  const float* xr = x + (size_t)row * H_;
  float4 v0 = *(const float4*)(xr + t * 4);
  float4 v1 = *(const float4*)(xr + 1024 + t * 4);
  float s  = v0.x + v0.y + v0.z + v0.w + v1.x + v1.y + v1.z + v1.w;
  float sq = v0.x*v0.x + v0.y*v0.y + v0.z*v0.z + v0.w*v0.w
           + v1.x*v1.x + v1.y*v1.y + v1.z*v1.z + v1.w*v1.w;
  #pragma unroll
  for (int m = 32; m; m >>= 1) { s += __shfl_xor(s, m); sq += __shfl_xor(sq, m); }
  __shared__ float red[8];
  int wv = t >> 6;
  if ((t & 63) == 0) { red[wv * 2] = s; red[wv * 2 + 1] = sq; }
  __syncthreads();
  s  = red[0] + red[2] + red[4] + red[6];
  sq = red[1] + red[3] + red[5] + red[7];
  float mu  = s * (1.0f / H_);
  float var = sq * (1.0f / H_) - mu * mu;
  float rs  = rsqrtf(var + 1e-5f);

  float4 w0 = *(const float4*)(w + t * 4);
  float4 b0 = *(const float4*)(b + t * 4);
  float4 w1 = *(const float4*)(w + 1024 + t * 4);
  float4 b1 = *(const float4*)(b + 1024 + t * 4);
  ushort4 o0, o1;
  o0.x = f2bf((v0.x - mu) * rs * w0.x + b0.x);
  o0.y = f2bf((v0.y - mu) * rs * w0.y + b0.y);
  o0.z = f2bf((v0.z - mu) * rs * w0.z + b0.z);
  o0.w = f2bf((v0.w - mu) * rs * w0.w + b0.w);
  o1.x = f2bf((v1.x - mu) * rs * w1.x + b1.x);
  o1.y = f2bf((v1.y - mu) * rs * w1.y + b1.y);
  o1.z = f2bf((v1.z - mu) * rs * w1.z + b1.z);
  o1.w = f2bf((v1.w - mu) * rs * w1.w + b1.w);
  unsigned short* orow = xn + (size_t)row * H_;
  *(ushort4*)(orow + t * 4) = o0;
  *(ushort4*)(orow + 1024 + t * 4) = o1;
}

// ------------------------------------------- fp32 [R][C] -> bf16 [C][R] (Wt)
__global__ __launch_bounds__(256) void transpose_f2b(
    const float* __restrict__ in, unsigned short* __restrict__ out,
    int R, int C) {
  __shared__ float tile[32][33];
  int tx = threadIdx.x & 31, ty = threadIdx.x >> 5;   // ty 0..7
  int c0 = blockIdx.x * 32, r0 = blockIdx.y * 32;
  #pragma unroll
  for (int i = 0; i < 32; i += 8)
    tile[ty + i][tx] = in[(size_t)(r0 + ty + i) * C + c0 + tx];
  __syncthreads();
  #pragma unroll
  for (int i = 0; i < 32; i += 8)
    out[(size_t)(c0 + ty + i) * R + r0 + tx] = f2bf(tile[tx][ty + i]);
}

// ===================================================================
// 256x256 GEMM core, register-pipelined (R2; kept as-is — near its
// LDS-BW structural ceiling, see R2/R3 post-mortems).
// ===================================================================
__device__ __forceinline__ void gemm256_acc(
    const unsigned short* __restrict__ A, const unsigned short* __restrict__ Bt,
    int m0, int n0, unsigned short (*sh)[16384], floatx4 (&acc)[8][4]) {
  const int t = threadIdx.x;
  const int lane = t & 63, wv = t >> 6;
  const int l15 = lane & 15, quad = lane >> 4;
  const int wm = wv >> 2, wn = wv & 3;
  const int x7 = l15 & 7;

  const int aRB = (wm * 128 + l15) * 64;
  const int bRB = (wn * 64 + l15) * 64;
  const int kx0 = ((0 + quad) ^ x7) * 8;
  const int kx1 = ((4 + quad) ^ x7) * 8;

  const int r = t >> 3, cc = t & 7;
  const int scol = (cc ^ (r & 7)) * 8;                 // swizzled SOURCE chunk
  const unsigned short* aSrc = A + (size_t)(m0 + r) * H_ + scol;
  const int btr = (r >> 5) * 64 + (r & 31);            // B-j01 tile row
  const unsigned short* bSrc = Bt + (size_t)(n0 + btr) * H_ + scol;
  const int aDst = t * 8;                              // shorts, lane-linear
  const int bDst = (r >> 5) * 4096 + (r & 31) * 64 + cc * 8;

  auto stageAll = [&](int kt, int buf) {               // 8 gl2lds, one K-tile
    const unsigned short* sa = aSrc + kt * 64;
    const unsigned short* sb = bSrc + kt * 64;
    unsigned short* da = sh[buf * 2] + aDst;
    unsigned short* db = sh[buf * 2 + 1] + bDst;
    gl2lds16(sa, da);
    gl2lds16(sa + (size_t)128 * H_, da + 8192);
    gl2lds16(sa + (size_t)64 * H_, da + 4096);
    gl2lds16(sa + (size_t)192 * H_, da + 12288);
    gl2lds16(sb, db);
    gl2lds16(sb + (size_t)128 * H_, db + 8192);
    gl2lds16(sb + (size_t)32 * H_, db + 2048);
    gl2lds16(sb + (size_t)160 * H_, db + 10240);
  };

  short8 aE[4][2], aO[4][2], b01[2][2], b23[2][2];
  auto readAE = [&](const unsigned short* Ab) {
    #pragma unroll
    for (int i = 0; i < 4; ++i) {
      aE[i][0] = *(const short8*)(Ab + aRB + i * 1024 + kx0);
      aE[i][1] = *(const short8*)(Ab + aRB + i * 1024 + kx1);
    }
  };
  auto readAO = [&](const unsigned short* Ab) {
    #pragma unroll
    for (int i = 0; i < 4; ++i) {
      aO[i][0] = *(const short8*)(Ab + aRB + (i + 4) * 1024 + kx0);
      aO[i][1] = *(const short8*)(Ab + aRB + (i + 4) * 1024 + kx1);
    }
  };
  auto readB01 = [&](const unsigned short* Bb) {
    #pragma unroll
    for (int j = 0; j < 2; ++j) {
      b01[j][0] = *(const short8*)(Bb + bRB + j * 1024 + kx0);
      b01[j][1] = *(const short8*)(Bb + bRB + j * 1024 + kx1);
    }
  };
  auto readB23 = [&](const unsigned short* Bb) {
    #pragma unroll
    for (int j = 0; j < 2; ++j) {
      b23[j][0] = *(const short8*)(Bb + bRB + (j + 2) * 1024 + kx0);
      b23[j][1] = *(const short8*)(Bb + bRB + (j + 2) * 1024 + kx1);
    }
  };

  #pragma unroll
  for (int i = 0; i < 8; i++)
    #pragma unroll
    for (int j = 0; j < 4; j++) acc[i][j] = (floatx4){0.f, 0.f, 0.f, 0.f};

  stageAll(0, 0);
  stageAll(1, 1);
  asm volatile("s_waitcnt vmcnt(8)" ::: "memory");     // tile0 landed
  __builtin_amdgcn_s_barrier();
  readAE(sh[0]); readB01(sh[1]);                       // q0 frags, tile0

  for (int n = 0; n < NT_; ++n) {
    const int buf = n & 1;
    const unsigned short* Ab = sh[buf * 2];
    const unsigned short* Bb = sh[buf * 2 + 1];

    readB23(Bb);
    asm volatile("s_waitcnt lgkmcnt(4)" ::: "memory");
    __builtin_amdgcn_sched_barrier(0);
    __builtin_amdgcn_s_setprio(1);
    #pragma unroll
    for (int i = 0; i < 4; ++i)
      #pragma unroll
      for (int j = 0; j < 2; ++j) {
        acc[i][j] = __builtin_amdgcn_mfma_f32_16x16x32_bf16(aE[i][0], b01[j][0], acc[i][j], 0, 0, 0);
        acc[i][j] = __builtin_amdgcn_mfma_f32_16x16x32_bf16(aE[i][1], b01[j][1], acc[i][j], 0, 0, 0);
      }
    __builtin_amdgcn_s_setprio(0);

    readAO(Ab);
    asm volatile("s_waitcnt lgkmcnt(8)" ::: "memory");
    __builtin_amdgcn_sched_barrier(0);
    __builtin_amdgcn_s_setprio(1);
    #pragma unroll
    for (int i = 0; i < 4; ++i)
      #pragma unroll
      for (int j = 0; j < 2; ++j) {
        acc[i][j + 2] = __builtin_amdgcn_mfma_f32_16x16x32_bf16(aE[i][0], b23[j][0], acc[i][j + 2], 0, 0, 0);
        acc[i][j + 2] = __builtin_amdgcn_mfma_f32_16x16x32_bf16(aE[i][1], b23[j][1], acc[i][j + 2], 0, 0, 0);
      }
    __builtin_amdgcn_s_setprio(0);

    asm volatile("s_waitcnt lgkmcnt(0)" ::: "memory");
    __builtin_amdgcn_sched_barrier(0);
    __builtin_amdgcn_s_setprio(1);
    #pragma unroll
    for (int i = 0; i < 4; ++i)
      #pragma unroll
      for (int j = 0; j < 2; ++j) {
        acc[i + 4][j] = __builtin_amdgcn_mfma_f32_16x16x32_bf16(aO[i][0], b01[j][0], acc[i + 4][j], 0, 0, 0);
        acc[i + 4][j] = __builtin_amdgcn_mfma_f32_16x16x32_bf16(aO[i][1], b01[j][1], acc[i + 4][j], 0, 0, 0);
      }
    __builtin_amdgcn_s_setprio(0);

    asm volatile("s_waitcnt vmcnt(0)" ::: "memory");
    __builtin_amdgcn_s_barrier();
    if (n + 1 < NT_) { readAE(sh[(buf ^ 1) * 2]); readB01(sh[(buf ^ 1) * 2 + 1]); }
    if (n + 2 < NT_) stageAll(n + 2, buf);

    __builtin_amdgcn_s_setprio(1);
    #pragma unroll
    for (int i = 0; i < 4; ++i)
      #pragma unroll
      for (int j = 0; j < 2; ++j) {
        acc[i + 4][j + 2] = __builtin_amdgcn_mfma_f32_16x16x32_bf16(aO[i][0], b23[j][0], acc[i + 4][j + 2], 0, 0, 0);
        acc[i + 4][j + 2] = __builtin_amdgcn_mfma_f32_16x16x32_bf16(aO[i][1], b23[j][1], acc[i + 4][j + 2], 0, 0, 0);
      }
    __builtin_amdgcn_s_setprio(0);
  }
}

// XCD-aware work mapping with L2-correct loop order (R1).
__device__ __forceinline__ void xcd_map(int& m0, int& n0) {
  int bid = blockIdx.y * gridDim.x + blockIdx.x;
  int xcd = bid & 7, loc = bid >> 3;
  m0 = ((xcd << 2) | (loc & 3)) * 256;
  n0 = (loc >> 2) * 256;
}

// ---------------------------------------------------------------- QKV GEMM
__global__ __launch_bounds__(512, 2) void qkv_gemm(
    const unsigned short* __restrict__ A, const unsigned short* __restrict__ Bt,
    const float* __restrict__ bias,
    unsigned short* __restrict__ qw, unsigned short* __restrict__ kw,
    unsigned short* __restrict__ vtw) {
  __shared__ unsigned short sh[4][16384];   // 128 KiB
  int m0, n0;
  xcd_map(m0, n0);

  floatx4 acc[8][4];
  gemm256_acc(A, Bt, m0, n0, sh, acc);

  int t = threadIdx.x, lane = t & 63, wv = t >> 6;
  int l15 = lane & 15, quad = lane >> 4;
  int wm = wv >> 2, wn = wv & 3;
  int sec = n0 >> 11;                       // 0:Q 1:K 2:V (256 | 2048)
  #pragma unroll
  for (int j = 0; j < 4; ++j) {
    int nn = n0 + wn * 64 + j * 16 + l15;
    int h = (nn >> 7) & 15;
    int d = nn & 127;
    float bval = bias[nn];
    #pragma unroll
    for (int i = 0; i < 8; ++i) {
      int m = m0 + wm * 128 + i * 16 + quad * 4;   // 4 consecutive rows
      int bb = m >> 11, s = m & 2047;
      int bh = bb * NH_ + h;
      if (sec == 2) {
        ushort4 pv;
        pv.x = f2bf(acc[i][j][0] + bval); pv.y = f2bf(acc[i][j][1] + bval);
        pv.z = f2bf(acc[i][j][2] + bval); pv.w = f2bf(acc[i][j][3] + bval);
        *(ushort4*)(vtw + ((size_t)bh * HD_ + d) * S_ + s) = pv;
      } else {
        unsigned short* dst = (sec == 0 ? qw : kw) + ((size_t)bh * S_ + s) * HD_ + d;
        #pragma unroll
        for (int reg = 0; reg < 4; reg++)
          dst[(size_t)reg * HD_] = f2bf(acc[i][j][reg] + bval);
      }
    }
  }
}

// ----------------------------------------------------------- Proj GEMM + res
__global__ __launch_bounds__(512, 2) void proj_gemm(
    const unsigned short* __restrict__ A, const unsigned short* __restrict__ Bt,
    const float* __restrict__ bias, const float* __restrict__ resid,
    float* __restrict__ out) {
  __shared__ unsigned short sh[4][16384];
  int m0, n0;
  xcd_map(m0, n0);

  floatx4 acc[8][4];
  gemm256_acc(A, Bt, m0, n0, sh, acc);

  int t = threadIdx.x, lane = t & 63, wv = t >> 6;
  int l15 = lane & 15, quad = lane >> 4;
  int wm = wv >> 2, wn = wv & 3;
  #pragma unroll
  for (int j = 0; j < 4; ++j) {
    int nn = n0 + wn * 64 + j * 16 + l15;
    float bval = bias[nn];
    #pragma unroll
    for (int i = 0; i < 8; ++i) {
      int m = m0 + wm * 128 + i * 16 + quad * 4;
      #pragma unroll
      for (int reg = 0; reg < 4; ++reg)
        out[(size_t)(m + reg) * H_ + nn] =
            acc[i][j][reg] + bval + resid[(size_t)(m + reg) * H_ + nn];
    }
  }
}

// ------------------------------------------------------- causal flash attn
// R4: 2-qsub structure (32 q-rows/wave) + __launch_bounds__(256,3) to pin
// VGPR <= 170 -> 3 waves/SIMD (R3 regressed because unbounded VGPR crossed
// the 171 boundary -> 2 waves/SIMD, occupancy -33%; m69 pool = 512/SIMD).
__global__ __launch_bounds__(256, 3) void attn_kernel(
    const unsigned short* __restrict__ qw, const unsigned short* __restrict__ kw,
    const unsigned short* __restrict__ vtw, unsigned short* __restrict__ ow) {
  __shared__ unsigned short Klds[64 * 136];   // [key 64][d 128 + pad]
  __shared__ unsigned short Vtl[128 * 72];    // [d 128][key 64 + pad]
  __shared__ unsigned short Pl[4][16 * 72];   // [wave][q 16][key 64 + pad]
  int pr = blockIdx.x, bh = blockIdx.y;
  int t = threadIdx.x, lane = t & 63, wv = t >> 6;
  int l15 = lane & 15, quad = lane >> 4;
  int h = bh & 15, bb = bh >> 4;

  const float scale = 0.08838834764831845f;
  int krr = t >> 4, kcc = (t & 15) * 8;       // K staging: 16 lanes/row
  int vdd = t >> 3, vss = (t & 7) * 8;        // Vt staging: 8 lanes/row
  unsigned short* plw = &Pl[wv][0];
  const unsigned short* kgb = kw + ((size_t)bh * S_ + krr) * HD_ + kcc;
  const unsigned short* vgb = vtw + ((size_t)bh * HD_ + vdd) * S_ + vss;

  short8 kreg[4], vreg[4];
  auto load_stage = [&](int kb) {
    #pragma unroll
    for (int c = 0; c < 4; c++) {
      kreg[c] = *(const short8*)(kgb + (size_t)(kb + c * 16) * HD_);
      vreg[c] = *(const short8*)(vgb + (size_t)(c * 32) * S_ + kb);
    }
  };

  #pragma unroll 1
  for (int half = 0; half < 2; half++) {
    int qtLo = half ? (30 - 2 * pr) : (2 * pr);
    int qtHi = qtLo + 1;                      // block covers q-tiles qtLo,qtHi
    int qr = qtLo * 64 + wv * 32;             // this wave's 32 q-rows
    int q0 = qr + l15;                        // qsub0 row
    int q1 = qr + 16 + l15;                   // qsub1 row

    short8 qf0[4], qf1[4];
    {
      const unsigned short* qb0 = qw + ((size_t)bh * S_ + q0) * HD_ + quad * 8;
      const unsigned short* qb1 = qw + ((size_t)bh * S_ + q1) * HD_ + quad * 8;
      #pragma unroll
      for (int ks = 0; ks < 4; ks++) {
        qf0[ks] = *(const short8*)(qb0 + ks * 32);
        qf1[ks] = *(const short8*)(qb1 + ks * 32);
      }
    }

    float m_i0 = -INFINITY, l_i0 = 0.f;
    float m_i1 = -INFINITY, l_i1 = 0.f;
    floatx4 o0[8], o1[8];
    #pragma unroll
    for (int ht = 0; ht < 8; ht++) {
      o0[ht] = (floatx4){0.f, 0.f, 0.f, 0.f};
      o1[ht] = (floatx4){0.f, 0.f, 0.f, 0.f};
    }

    load_stage(0);                            // prime the pipeline
    #pragma unroll 1
    for (int kt = 0; kt <= qtHi; kt++) {
      int kb = kt * 64;
      __syncthreads();                        // prev tile's LDS reads done
      #pragma unroll
      for (int c = 0; c < 4; c++) {
        *(short8*)(Klds + (c * 16 + krr) * 136 + kcc) = kreg[c];
        *(short8*)(Vtl + (c * 32 + vdd) * 72 + vss) = vreg[c];
      }
      __syncthreads();                        // tile visible to all waves
      if (kt < qtHi) load_stage(kb + 64);     // prefetch overlaps compute

      // ---- S^T = K.Q^T for both qsubs, kf read ONCE
      floatx4 sv0[4], sv1[4];
      __builtin_amdgcn_s_setprio(1);
      #pragma unroll
      for (int jm = 0; jm < 4; jm++) {
        sv0[jm] = (floatx4){0.f, 0.f, 0.f, 0.f};
        sv1[jm] = (floatx4){0.f, 0.f, 0.f, 0.f};
        #pragma unroll
        for (int ks = 0; ks < 4; ks++) {
          short8 kf = *(const short8*)(Klds + (jm * 16 + l15) * 136 + ks * 32 + quad * 8);
          sv0[jm] = __builtin_amdgcn_mfma_f32_16x16x32_bf16(kf, qf0[ks], sv0[jm], 0, 0, 0);
          sv1[jm] = __builtin_amdgcn_mfma_f32_16x16x32_bf16(kf, qf1[ks], sv1[jm], 0, 0, 0);
        }
      }
      __builtin_amdgcn_s_setprio(0);

      short8 pf0[2], pf1[2];
      // ---- softmax qsub0 (defer-max THR=8), P write, pf0 to regs
      {
        float p[4][4];
        float pmax = -INFINITY;
        #pragma unroll
        for (int jm = 0; jm < 4; jm++)
          #pragma unroll
          for (int reg = 0; reg < 4; reg++) {
            float v = sv0[jm][reg] * scale;
            int key = kb + jm * 16 + quad * 4 + reg;
            if (key > q0) v = -1e30f;
            p[jm][reg] = v;
            pmax = fmaxf(pmax, v);
          }
        pmax = fmaxf(pmax, __shfl_xor(pmax, 16));
        pmax = fmaxf(pmax, __shfl_xor(pmax, 32));
        if (!__all(pmax - m_i0 <= 8.f)) {
          float mnew = fmaxf(m_i0, pmax);
          float alpha = __expf(m_i0 - mnew);
          l_i0 *= alpha;
          #pragma unroll
          for (int ht = 0; ht < 8; ht++) o0[ht] *= alpha;
          m_i0 = mnew;
        }
        float sum = 0.f;
        #pragma unroll
        for (int jm = 0; jm < 4; jm++)
          #pragma unroll
          for (int reg = 0; reg < 4; reg++) { p[jm][reg] = __expf(p[jm][reg] - m_i0); sum += p[jm][reg]; }
        sum += __shfl_xor(sum, 16);
        sum += __shfl_xor(sum, 32);
        l_i0 += sum;
        #pragma unroll
        for (int jm = 0; jm < 4; jm++) {
          ushort4 pk;
          pk.x = f2bf(p[jm][0]); pk.y = f2bf(p[jm][1]);
          pk.z = f2bf(p[jm][2]); pk.w = f2bf(p[jm][3]);
          *(ushort4*)(plw + l15 * 72 + jm * 16 + quad * 4) = pk;
        }
        pf0[0] = *(const short8*)(plw + l15 * 72 + quad * 8);
        pf0[1] = *(const short8*)(plw + l15 * 72 + 32 + quad * 8);
      }
      // ---- softmax qsub1 (reuses Pl; wave-private DS pipe is in-order,
      // pf0 reads were issued before these writes)
      {
        float p[4][4];
        float pmax = -INFINITY;
        #pragma unroll
        for (int jm = 0; jm < 4; jm++)
          #pragma unroll
          for (int reg = 0; reg < 4; reg++) {
            float v = sv1[jm][reg] * scale;
            int key = kb + jm * 16 + quad * 4 + reg;
            if (key > q1) v = -1e30f;
            p[jm][reg] = v;
            pmax = fmaxf(pmax, v);
          }
        pmax = fmaxf(pmax, __shfl_xor(pmax, 16));
        pmax = fmaxf(pmax, __shfl_xor(pmax, 32));
        if (!__all(pmax - m_i1 <= 8.f)) {
          float mnew = fmaxf(m_i1, pmax);
          float alpha = __expf(m_i1 - mnew);
          l_i1 *= alpha;
          #pragma unroll
          for (int ht = 0; ht < 8; ht++) o1[ht] *= alpha;
          m_i1 = mnew;
        }
        float sum = 0.f;
        #pragma unroll
        for (int jm = 0; jm < 4; jm++)
          #pragma unroll
          for (int reg = 0; reg < 4; reg++) { p[jm][reg] = __expf(p[jm][reg] - m_i1); sum += p[jm][reg]; }
        sum += __shfl_xor(sum, 16);
        sum += __shfl_xor(sum, 32);
        l_i1 += sum;
        #pragma unroll
        for (int jm = 0; jm < 4; jm++) {
          ushort4 pk;
          pk.x = f2bf(p[jm][0]); pk.y = f2bf(p[jm][1]);
          pk.z = f2bf(p[jm][2]); pk.w = f2bf(p[jm][3]);
          *(ushort4*)(plw + l15 * 72 + jm * 16 + quad * 4) = pk;
        }
        pf1[0] = *(const short8*)(plw + l15 * 72 + quad * 8);
        pf1[1] = *(const short8*)(plw + l15 * 72 + 32 + quad * 8);
      }

      // ---- O^T += V^T.P^T for both qsubs, vf read ONCE
      __builtin_amdgcn_s_setprio(1);
      #pragma unroll
      for (int ks2 = 0; ks2 < 2; ks2++) {
        #pragma unroll
        for (int ht = 0; ht < 8; ht++) {
          short8 vf = *(const short8*)(Vtl + (ht * 16 + l15) * 72 + ks2 * 32 + quad * 8);
          o0[ht] = __builtin_amdgcn_mfma_f32_16x16x32_bf16(vf, pf0[ks2], o0[ht], 0, 0, 0);
          o1[ht] = __builtin_amdgcn_mfma_f32_16x16x32_bf16(vf, pf1[ks2], o1[ht], 0, 0, 0);
        }
      }
      __builtin_amdgcn_s_setprio(0);
    }

    // ---- epilogue, both qsubs
    {
      float inv = 1.0f / l_i0;
      size_t base = ((size_t)(bb * S_ + q0)) * H_ + h * HD_ + quad * 4;
      #pragma unroll
      for (int ht = 0; ht < 8; ht++) {
        ushort4 ov;
        ov.x = f2bf(o0[ht][0] * inv); ov.y = f2bf(o0[ht][1] * inv);
        ov.z = f2bf(o0[ht][2] * inv); ov.w = f2bf(o0[ht][3] * inv);
        *(ushort4*)(ow + base + ht * 16) = ov;
      }
    }
    {
      float inv = 1.0f / l_i1;
      size_t base = ((size_t)(bb * S_ + q1)) * H_ + h * HD_ + quad * 4;
      #pragma unroll
      for (int ht = 0; ht < 8; ht++) {
        ushort4 ov;
        ov.x = f2bf(o1[ht][0] * inv); ov.y = f2bf(o1[ht][1] * inv);
        ov.z = f2bf(o1[ht][2] * inv); ov.w = f2bf(o1[ht][3] * inv);
        *(ushort4*)(ow + base + ht * 16) = ov;
      }
    }
  }
}

// ---------------------------------------------------------------- launcher
extern "C" void kernel_launch(void* const* d_in, const int* in_sizes, int n_in,
                              void* d_out, int out_size, void* d_ws, size_t ws_size,
                              hipStream_t stream) {
  (void)in_sizes; (void)n_in; (void)out_size; (void)ws_size;
  const float* x      = (const float*)d_in[0];
  const float* ln_w   = (const float*)d_in[1];
  const float* ln_b   = (const float*)d_in[2];
  const float* attn_w = (const float*)d_in[3];
  const float* attn_b = (const float*)d_in[4];
  const float* proj_w = (const float*)d_in[5];
  const float* proj_b = (const float*)d_in[6];
  float* out = (float*)d_out;

  char* ws = (char*)d_ws;
  size_t off = 0;
  auto alloc = [&](size_t bytes) {
    char* p = ws + off;
    off += (bytes + 255) & ~(size_t)255;
    return p;
  };
  unsigned short* xn     = (unsigned short*)alloc((size_t)M_ * H_ * 2);
  unsigned short* wqkvt  = (unsigned short*)alloc((size_t)N3_ * H_ * 2);
  unsigned short* wprojt = (unsigned short*)alloc((size_t)H_ * H_ * 2);
  unsigned short* qws    = (unsigned short*)alloc((size_t)M_ * H_ * 2);
  unsigned short* kws    = (unsigned short*)alloc((size_t)M_ * H_ * 2);
  unsigned short* vtws   = (unsigned short*)alloc((size_t)M_ * H_ * 2);
  unsigned short* attn_out = xn;   // xn dead after qkv_gemm — alias

  ln_kernel<<<M_, 256, 0, stream>>>(x, ln_w, ln_b, xn);
  transpose_f2b<<<dim3(N3_ / 32, H_ / 32), 256, 0, stream>>>(attn_w, wqkvt, H_, N3_);
  transpose_f2b<<<dim3(H_ / 32, H_ / 32), 256, 0, stream>>>(proj_w, wprojt, H_, H_);
  qkv_gemm<<<dim3(N3_ / 256, M_ / 256), 512, 0, stream>>>(xn, wqkvt, attn_b, qws, kws, vtws);
  attn_kernel<<<dim3(NQT_ / 4, B_ * NH_), 256, 0, stream>>>(qws, kws, vtws, attn_out);
  proj_gemm<<<dim3(H_ / 256, M_ / 256), 512, 0, stream>>>(attn_out, wprojt, proj_b, x, out);
}

// Round 6
// 605.026 us; speedup vs baseline: 1.3311x; 1.3311x over previous
//
#include <hip/hip_runtime.h>
#include <stdint.h>
#include <math.h>

#define B_  4
#define S_  2048
#define H_  2048
#define NH_ 16
#define HD_ 128
#define M_  (B_*S_)     // 8192 rows
#define N3_ (3*H_)      // 6144
#define NQT_ (S_/64)    // 32 q-tiles of 64 rows
#define NT_ (H_/64)     // 32 K-tiles for the GEMMs

typedef __attribute__((ext_vector_type(8))) short short8;
typedef __attribute__((ext_vector_type(4))) float floatx4;
typedef unsigned int u32;

__device__ __forceinline__ unsigned short f2bf(float f) {
  unsigned u = __float_as_uint(f);
  u += 0x7FFF + ((u >> 16) & 1);          // round-to-nearest-even
  return (unsigned short)(u >> 16);
}

// async 16B global -> LDS (global_load_lds_dwordx4). LDS dest must be
// wave-uniform base + lane*16 (no per-lane scatter / padding!).
__device__ __forceinline__ void gl2lds16(const void* g, void* l) {
  __builtin_amdgcn_global_load_lds(
      (const __attribute__((address_space(1))) u32*)g,
      (__attribute__((address_space(3))) u32*)l, 16, 0, 0);
}

// ---------------------------------------------------------------- LayerNorm
__global__ __launch_bounds__(256) void ln_kernel(
    const float* __restrict__ x, const float* __restrict__ w,
    const float* __restrict__ b, unsigned short* __restrict__ xn) {
  int row = blockIdx.x;
  int t = threadIdx.x;
  const float* xr = x + (size_t)row * H_;
  float4 v0 = *(const float4*)(xr + t * 4);
  float4 v1 = *(const float4*)(xr + 1024 + t * 4);
  float s  = v0.x + v0.y + v0.z + v0.w + v1.x + v1.y + v1.z + v1.w;
  float sq = v0.x*v0.x + v0.y*v0.y + v0.z*v0.z + v0.w*v0.w
           + v1.x*v1.x + v1.y*v1.y + v1.z*v1.z + v1.w*v1.w;
  #pragma unroll
  for (int m = 32; m; m >>= 1) { s += __shfl_xor(s, m); sq += __shfl_xor(sq, m); }
  __shared__ float red[8];
  int wv = t >> 6;
  if ((t & 63) == 0) { red[wv * 2] = s; red[wv * 2 + 1] = sq; }
  __syncthreads();
  s  = red[0] + red[2] + red[4] + red[6];
  sq = red[1] + red[3] + red[5] + red[7];
  float mu  = s * (1.0f / H_);
  float var = sq * (1.0f / H_) - mu * mu;
  float rs  = rsqrtf(var + 1e-5f);

  float4 w0 = *(const float4*)(w + t * 4);
  float4 b0 = *(const float4*)(b + t * 4);
  float4 w1 = *(const float4*)(w + 1024 + t * 4);
  float4 b1 = *(const float4*)(b + 1024 + t * 4);
  ushort4 o0, o1;
  o0.x = f2bf((v0.x - mu) * rs * w0.x + b0.x);
  o0.y = f2bf((v0.y - mu) * rs * w0.y + b0.y);
  o0.z = f2bf((v0.z - mu) * rs * w0.z + b0.z);
  o0.w = f2bf((v0.w - mu) * rs * w0.w + b0.w);
  o1.x = f2bf((v1.x - mu) * rs * w1.x + b1.x);
  o1.y = f2bf((v1.y - mu) * rs * w1.y + b1.y);
  o1.z = f2bf((v1.z - mu) * rs * w1.z + b1.z);
  o1.w = f2bf((v1.w - mu) * rs * w1.w + b1.w);
  unsigned short* orow = xn + (size_t)row * H_;
  *(ushort4*)(orow + t * 4) = o0;
  *(ushort4*)(orow + 1024 + t * 4) = o1;
}

// ------------------------------------------- fp32 [R][C] -> bf16 [C][R] (Wt)
__global__ __launch_bounds__(256) void transpose_f2b(
    const float* __restrict__ in, unsigned short* __restrict__ out,
    int R, int C) {
  __shared__ float tile[32][33];
  int tx = threadIdx.x & 31, ty = threadIdx.x >> 5;   // ty 0..7
  int c0 = blockIdx.x * 32, r0 = blockIdx.y * 32;
  #pragma unroll
  for (int i = 0; i < 32; i += 8)
    tile[ty + i][tx] = in[(size_t)(r0 + ty + i) * C + c0 + tx];
  __syncthreads();
  #pragma unroll
  for (int i = 0; i < 32; i += 8)
    out[(size_t)(c0 + ty + i) * R + r0 + tx] = f2bf(tile[tx][ty + i]);
}

// ===================================================================
// 256x256 GEMM core, register-pipelined (R2; kept frozen — R2/R3 showed
// it at ~42% MfmaUtil; residual gap is wave-level stall, parked).
// ===================================================================
__device__ __forceinline__ void gemm256_acc(
    const unsigned short* __restrict__ A, const unsigned short* __restrict__ Bt,
    int m0, int n0, unsigned short (*sh)[16384], floatx4 (&acc)[8][4]) {
  const int t = threadIdx.x;
  const int lane = t & 63, wv = t >> 6;
  const int l15 = lane & 15, quad = lane >> 4;
  const int wm = wv >> 2, wn = wv & 3;
  const int x7 = l15 & 7;

  const int aRB = (wm * 128 + l15) * 64;
  const int bRB = (wn * 64 + l15) * 64;
  const int kx0 = ((0 + quad) ^ x7) * 8;
  const int kx1 = ((4 + quad) ^ x7) * 8;

  const int r = t >> 3, cc = t & 7;
  const int scol = (cc ^ (r & 7)) * 8;                 // swizzled SOURCE chunk
  const unsigned short* aSrc = A + (size_t)(m0 + r) * H_ + scol;
  const int btr = (r >> 5) * 64 + (r & 31);            // B-j01 tile row
  const unsigned short* bSrc = Bt + (size_t)(n0 + btr) * H_ + scol;
  const int aDst = t * 8;                              // shorts, lane-linear
  const int bDst = (r >> 5) * 4096 + (r & 31) * 64 + cc * 8;

  auto stageAll = [&](int kt, int buf) {               // 8 gl2lds, one K-tile
    const unsigned short* sa = aSrc + kt * 64;
    const unsigned short* sb = bSrc + kt * 64;
    unsigned short* da = sh[buf * 2] + aDst;
    unsigned short* db = sh[buf * 2 + 1] + bDst;
    gl2lds16(sa, da);
    gl2lds16(sa + (size_t)128 * H_, da + 8192);
    gl2lds16(sa + (size_t)64 * H_, da + 4096);
    gl2lds16(sa + (size_t)192 * H_, da + 12288);
    gl2lds16(sb, db);
    gl2lds16(sb + (size_t)128 * H_, db + 8192);
    gl2lds16(sb + (size_t)32 * H_, db + 2048);
    gl2lds16(sb + (size_t)160 * H_, db + 10240);
  };

  short8 aE[4][2], aO[4][2], b01[2][2], b23[2][2];
  auto readAE = [&](const unsigned short* Ab) {
    #pragma unroll
    for (int i = 0; i < 4; ++i) {
      aE[i][0] = *(const short8*)(Ab + aRB + i * 1024 + kx0);
      aE[i][1] = *(const short8*)(Ab + aRB + i * 1024 + kx1);
    }
  };
  auto readAO = [&](const unsigned short* Ab) {
    #pragma unroll
    for (int i = 0; i < 4; ++i) {
      aO[i][0] = *(const short8*)(Ab + aRB + (i + 4) * 1024 + kx0);
      aO[i][1] = *(const short8*)(Ab + aRB + (i + 4) * 1024 + kx1);
    }
  };
  auto readB01 = [&](const unsigned short* Bb) {
    #pragma unroll
    for (int j = 0; j < 2; ++j) {
      b01[j][0] = *(const short8*)(Bb + bRB + j * 1024 + kx0);
      b01[j][1] = *(const short8*)(Bb + bRB + j * 1024 + kx1);
    }
  };
  auto readB23 = [&](const unsigned short* Bb) {
    #pragma unroll
    for (int j = 0; j < 2; ++j) {
      b23[j][0] = *(const short8*)(Bb + bRB + (j + 2) * 1024 + kx0);
      b23[j][1] = *(const short8*)(Bb + bRB + (j + 2) * 1024 + kx1);
    }
  };

  #pragma unroll
  for (int i = 0; i < 8; i++)
    #pragma unroll
    for (int j = 0; j < 4; j++) acc[i][j] = (floatx4){0.f, 0.f, 0.f, 0.f};

  stageAll(0, 0);
  stageAll(1, 1);
  asm volatile("s_waitcnt vmcnt(8)" ::: "memory");     // tile0 landed
  __builtin_amdgcn_s_barrier();
  readAE(sh[0]); readB01(sh[1]);                       // q0 frags, tile0

  for (int n = 0; n < NT_; ++n) {
    const int buf = n & 1;
    const unsigned short* Ab = sh[buf * 2];
    const unsigned short* Bb = sh[buf * 2 + 1];

    readB23(Bb);
    asm volatile("s_waitcnt lgkmcnt(4)" ::: "memory");
    __builtin_amdgcn_sched_barrier(0);
    __builtin_amdgcn_s_setprio(1);
    #pragma unroll
    for (int i = 0; i < 4; ++i)
      #pragma unroll
      for (int j = 0; j < 2; ++j) {
        acc[i][j] = __builtin_amdgcn_mfma_f32_16x16x32_bf16(aE[i][0], b01[j][0], acc[i][j], 0, 0, 0);
        acc[i][j] = __builtin_amdgcn_mfma_f32_16x16x32_bf16(aE[i][1], b01[j][1], acc[i][j], 0, 0, 0);
      }
    __builtin_amdgcn_s_setprio(0);

    readAO(Ab);
    asm volatile("s_waitcnt lgkmcnt(8)" ::: "memory");
    __builtin_amdgcn_sched_barrier(0);
    __builtin_amdgcn_s_setprio(1);
    #pragma unroll
    for (int i = 0; i < 4; ++i)
      #pragma unroll
      for (int j = 0; j < 2; ++j) {
        acc[i][j + 2] = __builtin_amdgcn_mfma_f32_16x16x32_bf16(aE[i][0], b23[j][0], acc[i][j + 2], 0, 0, 0);
        acc[i][j + 2] = __builtin_amdgcn_mfma_f32_16x16x32_bf16(aE[i][1], b23[j][1], acc[i][j + 2], 0, 0, 0);
      }
    __builtin_amdgcn_s_setprio(0);

    asm volatile("s_waitcnt lgkmcnt(0)" ::: "memory");
    __builtin_amdgcn_sched_barrier(0);
    __builtin_amdgcn_s_setprio(1);
    #pragma unroll
    for (int i = 0; i < 4; ++i)
      #pragma unroll
      for (int j = 0; j < 2; ++j) {
        acc[i + 4][j] = __builtin_amdgcn_mfma_f32_16x16x32_bf16(aO[i][0], b01[j][0], acc[i + 4][j], 0, 0, 0);
        acc[i + 4][j] = __builtin_amdgcn_mfma_f32_16x16x32_bf16(aO[i][1], b01[j][1], acc[i + 4][j], 0, 0, 0);
      }
    __builtin_amdgcn_s_setprio(0);

    asm volatile("s_waitcnt vmcnt(0)" ::: "memory");
    __builtin_amdgcn_s_barrier();
    if (n + 1 < NT_) { readAE(sh[(buf ^ 1) * 2]); readB01(sh[(buf ^ 1) * 2 + 1]); }
    if (n + 2 < NT_) stageAll(n + 2, buf);

    __builtin_amdgcn_s_setprio(1);
    #pragma unroll
    for (int i = 0; i < 4; ++i)
      #pragma unroll
      for (int j = 0; j < 2; ++j) {
        acc[i + 4][j + 2] = __builtin_amdgcn_mfma_f32_16x16x32_bf16(aO[i][0], b23[j][0], acc[i + 4][j + 2], 0, 0, 0);
        acc[i + 4][j + 2] = __builtin_amdgcn_mfma_f32_16x16x32_bf16(aO[i][1], b23[j][1], acc[i + 4][j + 2], 0, 0, 0);
      }
    __builtin_amdgcn_s_setprio(0);
  }
}

// XCD-aware work mapping with L2-correct loop order (R1).
__device__ __forceinline__ void xcd_map(int& m0, int& n0) {
  int bid = blockIdx.y * gridDim.x + blockIdx.x;
  int xcd = bid & 7, loc = bid >> 3;
  m0 = ((xcd << 2) | (loc & 3)) * 256;
  n0 = (loc >> 2) * 256;
}

// ---------------------------------------------------------------- QKV GEMM
__global__ __launch_bounds__(512, 2) void qkv_gemm(
    const unsigned short* __restrict__ A, const unsigned short* __restrict__ Bt,
    const float* __restrict__ bias,
    unsigned short* __restrict__ qw, unsigned short* __restrict__ kw,
    unsigned short* __restrict__ vtw) {
  __shared__ unsigned short sh[4][16384];   // 128 KiB
  int m0, n0;
  xcd_map(m0, n0);

  floatx4 acc[8][4];
  gemm256_acc(A, Bt, m0, n0, sh, acc);

  int t = threadIdx.x, lane = t & 63, wv = t >> 6;
  int l15 = lane & 15, quad = lane >> 4;
  int wm = wv >> 2, wn = wv & 3;
  int sec = n0 >> 11;                       // 0:Q 1:K 2:V (256 | 2048)
  #pragma unroll
  for (int j = 0; j < 4; ++j) {
    int nn = n0 + wn * 64 + j * 16 + l15;
    int h = (nn >> 7) & 15;
    int d = nn & 127;
    float bval = bias[nn];
    #pragma unroll
    for (int i = 0; i < 8; ++i) {
      int m = m0 + wm * 128 + i * 16 + quad * 4;   // 4 consecutive rows
      int bb = m >> 11, s = m & 2047;
      int bh = bb * NH_ + h;
      if (sec == 2) {
        ushort4 pv;
        pv.x = f2bf(acc[i][j][0] + bval); pv.y = f2bf(acc[i][j][1] + bval);
        pv.z = f2bf(acc[i][j][2] + bval); pv.w = f2bf(acc[i][j][3] + bval);
        *(ushort4*)(vtw + ((size_t)bh * HD_ + d) * S_ + s) = pv;
      } else {
        unsigned short* dst = (sec == 0 ? qw : kw) + ((size_t)bh * S_ + s) * HD_ + d;
        #pragma unroll
        for (int reg = 0; reg < 4; reg++)
          dst[(size_t)reg * HD_] = f2bf(acc[i][j][reg] + bval);
      }
    }
  }
}

// ----------------------------------------------------------- Proj GEMM + res
__global__ __launch_bounds__(512, 2) void proj_gemm(
    const unsigned short* __restrict__ A, const unsigned short* __restrict__ Bt,
    const float* __restrict__ bias, const float* __restrict__ resid,
    float* __restrict__ out) {
  __shared__ unsigned short sh[4][16384];
  int m0, n0;
  xcd_map(m0, n0);

  floatx4 acc[8][4];
  gemm256_acc(A, Bt, m0, n0, sh, acc);

  int t = threadIdx.x, lane = t & 63, wv = t >> 6;
  int l15 = lane & 15, quad = lane >> 4;
  int wm = wv >> 2, wn = wv & 3;
  #pragma unroll
  for (int j = 0; j < 4; ++j) {
    int nn = n0 + wn * 64 + j * 16 + l15;
    float bval = bias[nn];
    #pragma unroll
    for (int i = 0; i < 8; ++i) {
      int m = m0 + wm * 128 + i * 16 + quad * 4;
      #pragma unroll
      for (int reg = 0; reg < 4; ++reg)
        out[(size_t)(m + reg) * H_ + nn] =
            acc[i][j][reg] + bval + resid[(size_t)(m + reg) * H_ + nn];
    }
  }
}

// ------------------------------------------------------- causal flash attn
// R6: exact R3-config attn (1 qsub/wave — best measured config; 2-qsub dead:
// R4 unbounded = 2 waves/SIMD, R5 bounded = spill) + XCD-aware bh grouping:
// the 16 blocks sharing a head's K/V (0.5 MB) now land on ONE XCD so K/V
// stay L2-resident instead of being refetched by all 8 XCDs (T1; attn has
// the inter-block reuse that makes T1 applicable).
__global__ __launch_bounds__(256) void attn_kernel(
    const unsigned short* __restrict__ qw, const unsigned short* __restrict__ kw,
    const unsigned short* __restrict__ vtw, unsigned short* __restrict__ ow) {
  __shared__ unsigned short Klds[64 * 136];   // [key 64][d 128 + pad]
  __shared__ unsigned short Vtl[128 * 72];    // [d 128][key 64 + pad]
  __shared__ unsigned short Pl[4][16 * 72];   // [wave][q 16][key 64 + pad]
  // XCD swizzle: nwg = 16*64 = 1024 (%8==0). XCD x owns swz range
  // [x*128, (x+1)*128) = bh in [x*8, x*8+8), each bh complete on one XCD.
  int bid0 = blockIdx.y * gridDim.x + blockIdx.x;
  int swz = (bid0 & 7) * 128 + (bid0 >> 3);
  int pr = swz & 15, bh = swz >> 4;
  int t = threadIdx.x, lane = t & 63, wv = t >> 6;
  int l15 = lane & 15, quad = lane >> 4;
  int h = bh & 15, bb = bh >> 4;

  const float scale = 0.08838834764831845f;
  int krr = t >> 4, kcc = (t & 15) * 8;       // K staging: 16 lanes/row
  int vdd = t >> 3, vss = (t & 7) * 8;        // Vt staging: 8 lanes/row
  unsigned short* plw = &Pl[wv][0];
  const unsigned short* kgb = kw + ((size_t)bh * S_ + krr) * HD_ + kcc;
  const unsigned short* vgb = vtw + ((size_t)bh * HD_ + vdd) * S_ + vss;

  short8 kreg[4], vreg[4];
  auto load_stage = [&](int kb) {
    #pragma unroll
    for (int c = 0; c < 4; c++) {
      kreg[c] = *(const short8*)(kgb + (size_t)(kb + c * 16) * HD_);
      vreg[c] = *(const short8*)(vgb + (size_t)(c * 32) * S_ + kb);
    }
  };

  #pragma unroll 1
  for (int half = 0; half < 2; half++) {
    int qt = half ? (NQT_ - 1 - pr) : pr;
    int qr = qt * 64 + wv * 16;
    int q = qr + l15;                         // this lane's q-row

    short8 qf[4];
    {
      const unsigned short* qbase = qw + ((size_t)bh * S_ + q) * HD_ + quad * 8;
      #pragma unroll
      for (int ks = 0; ks < 4; ks++)
        qf[ks] = *(const short8*)(qbase + ks * 32);
    }

    float m_i = -INFINITY, l_i = 0.f;
    floatx4 o[8];
    #pragma unroll
    for (int ht = 0; ht < 8; ht++) o[ht] = (floatx4){0.f, 0.f, 0.f, 0.f};

    load_stage(0);                            // prime the pipeline
    #pragma unroll 1
    for (int kt = 0; kt <= qt; kt++) {
      int kb = kt * 64;
      __syncthreads();                        // prev tile's LDS reads done
      #pragma unroll
      for (int c = 0; c < 4; c++) {
        *(short8*)(Klds + (c * 16 + krr) * 136 + kcc) = kreg[c];
        *(short8*)(Vtl + (c * 32 + vdd) * 72 + vss) = vreg[c];
      }
      __syncthreads();                        // tile visible to all waves
      if (kt < qt) load_stage(kb + 64);       // prefetch overlaps compute

      floatx4 sv[4];
      __builtin_amdgcn_s_setprio(1);
      #pragma unroll
      for (int jm = 0; jm < 4; jm++) {
        sv[jm] = (floatx4){0.f, 0.f, 0.f, 0.f};
        #pragma unroll
        for (int ks = 0; ks < 4; ks++) {
          short8 kf = *(const short8*)(Klds + (jm * 16 + l15) * 136 + ks * 32 + quad * 8);
          sv[jm] = __builtin_amdgcn_mfma_f32_16x16x32_bf16(kf, qf[ks], sv[jm], 0, 0, 0);
        }
      }
      __builtin_amdgcn_s_setprio(0);

      // ---- online softmax with defer-max (THR=8): lane holds 16 scores
      float p[4][4];
      float pmax = -INFINITY;
      #pragma unroll
      for (int jm = 0; jm < 4; jm++)
        #pragma unroll
        for (int reg = 0; reg < 4; reg++) {
          float v = sv[jm][reg] * scale;
          int key = kb + jm * 16 + quad * 4 + reg;
          if (key > q) v = -1e30f;
          p[jm][reg] = v;
          pmax = fmaxf(pmax, v);
        }
      pmax = fmaxf(pmax, __shfl_xor(pmax, 16));
      pmax = fmaxf(pmax, __shfl_xor(pmax, 32));
      if (!__all(pmax - m_i <= 8.f)) {        // rescale only on real growth
        float mnew = fmaxf(m_i, pmax);
        float alpha = __expf(m_i - mnew);
        l_i *= alpha;
        #pragma unroll
        for (int ht = 0; ht < 8; ht++) o[ht] *= alpha;
        m_i = mnew;
      }
      float sum = 0.f;
      #pragma unroll
      for (int jm = 0; jm < 4; jm++)
        #pragma unroll
        for (int reg = 0; reg < 4; reg++) { p[jm][reg] = __expf(p[jm][reg] - m_i); sum += p[jm][reg]; }
      sum += __shfl_xor(sum, 16);
      sum += __shfl_xor(sum, 32);
      l_i += sum;

      #pragma unroll
      for (int jm = 0; jm < 4; jm++) {
        ushort4 pk;
        pk.x = f2bf(p[jm][0]); pk.y = f2bf(p[jm][1]);
        pk.z = f2bf(p[jm][2]); pk.w = f2bf(p[jm][3]);
        *(ushort4*)(plw + l15 * 72 + jm * 16 + quad * 4) = pk;
      }

      __builtin_amdgcn_s_setprio(1);
      #pragma unroll
      for (int ks2 = 0; ks2 < 2; ks2++) {
        short8 pf = *(const short8*)(plw + l15 * 72 + ks2 * 32 + quad * 8);
        #pragma unroll
        for (int ht = 0; ht < 8; ht++) {
          short8 vf = *(const short8*)(Vtl + (ht * 16 + l15) * 72 + ks2 * 32 + quad * 8);
          o[ht] = __builtin_amdgcn_mfma_f32_16x16x32_bf16(vf, pf, o[ht], 0, 0, 0);
        }
      }
      __builtin_amdgcn_s_setprio(0);
    }

    float inv = 1.0f / l_i;
    size_t base = ((size_t)(bb * S_ + q)) * H_ + h * HD_ + quad * 4;
    #pragma unroll
    for (int ht = 0; ht < 8; ht++) {
      ushort4 ov;
      ov.x = f2bf(o[ht][0] * inv); ov.y = f2bf(o[ht][1] * inv);
      ov.z = f2bf(o[ht][2] * inv); ov.w = f2bf(o[ht][3] * inv);
      *(ushort4*)(ow + base + ht * 16) = ov;
    }
  }
}

// ---------------------------------------------------------------- launcher
extern "C" void kernel_launch(void* const* d_in, const int* in_sizes, int n_in,
                              void* d_out, int out_size, void* d_ws, size_t ws_size,
                              hipStream_t stream) {
  (void)in_sizes; (void)n_in; (void)out_size; (void)ws_size;
  const float* x      = (const float*)d_in[0];
  const float* ln_w   = (const float*)d_in[1];
  const float* ln_b   = (const float*)d_in[2];
  const float* attn_w = (const float*)d_in[3];
  const float* attn_b = (const float*)d_in[4];
  const float* proj_w = (const float*)d_in[5];
  const float* proj_b = (const float*)d_in[6];
  float* out = (float*)d_out;

  char* ws = (char*)d_ws;
  size_t off = 0;
  auto alloc = [&](size_t bytes) {
    char* p = ws + off;
    off += (bytes + 255) & ~(size_t)255;
    return p;
  };
  unsigned short* xn     = (unsigned short*)alloc((size_t)M_ * H_ * 2);
  unsigned short* wqkvt  = (unsigned short*)alloc((size_t)N3_ * H_ * 2);
  unsigned short* wprojt = (unsigned short*)alloc((size_t)H_ * H_ * 2);
  unsigned short* qws    = (unsigned short*)alloc((size_t)M_ * H_ * 2);
  unsigned short* kws    = (unsigned short*)alloc((size_t)M_ * H_ * 2);
  unsigned short* vtws   = (unsigned short*)alloc((size_t)M_ * H_ * 2);
  unsigned short* attn_out = xn;   // xn dead after qkv_gemm — alias

  ln_kernel<<<M_, 256, 0, stream>>>(x, ln_w, ln_b, xn);
  transpose_f2b<<<dim3(N3_ / 32, H_ / 32), 256, 0, stream>>>(attn_w, wqkvt, H_, N3_);
  transpose_f2b<<<dim3(H_ / 32, H_ / 32), 256, 0, stream>>>(proj_w, wprojt, H_, H_);
  qkv_gemm<<<dim3(N3_ / 256, M_ / 256), 512, 0, stream>>>(xn, wqkvt, attn_b, qws, kws, vtws);
  attn_kernel<<<dim3(NQT_ / 2, B_ * NH_), 256, 0, stream>>>(qws, kws, vtws, attn_out);
  proj_gemm<<<dim3(H_ / 256, M_ / 256), 512, 0, stream>>>(attn_out, wprojt, proj_b, x, out);
}